// Round 5
// baseline (740.263 us; speedup 1.0000x reference)
//
#include <hip/hip_runtime.h>
#include <hip/hip_bf16.h>

#define VOCAB  32000
#define EMBED  32
#define HIDDEN 16
#define SEQ    128
#define BATCH  32

typedef __attribute__((ext_vector_type(8))) short short8;
typedef __attribute__((ext_vector_type(4))) float float4v;

#define LOG2E 1.4426950408889634f
#define LN2   0.6931471805599453f

// k_out tiling: 256 blocks x 16 waves; each wave owns 125 of the 2000
// 16-vocab tiles (31 groups of 4 + 1 tail).
#define TPW_OUT 125

__device__ __forceinline__ float fexp2(float x) { return __builtin_amdgcn_exp2f(x); }
__device__ __forceinline__ float frcp(float x)  { return __builtin_amdgcn_rcpf(x); }
__device__ __forceinline__ float flog2(float x) { return __builtin_amdgcn_logf(x); }

// RTNE float -> bf16 bits (finite inputs only)
__device__ __forceinline__ unsigned short f2bf(float x) {
    unsigned u = __float_as_uint(x);
    unsigned r = u + 0x7fffu + ((u >> 16) & 1u);
    return (unsigned short)(r >> 16);
}

// ---------------------------------------------------------------------------
// Kernel 0: proj[v][j] = emb[v]·W_ih[j] + b_ih[j] + b_hh[j]   (fp32)
// 1000 blocks x 256 thr.  (R2-verified form.)
// ---------------------------------------------------------------------------
__global__ __launch_bounds__(256) void k_prep(
    const float* __restrict__ emb,
    const float* __restrict__ W_ih,
    const float* __restrict__ b_ih,
    const float* __restrict__ b_hh,
    float* __restrict__ proj)
{
    int j  = threadIdx.x & 63;
    int vl = threadIdx.x >> 6;          // 0..3
    int vbase = blockIdx.x * 32 + vl * 8;

    float w[32];
    {
        const float4* wp = (const float4*)(W_ih + j * 32);
#pragma unroll
        for (int i = 0; i < 8; ++i) *((float4*)w + i) = wp[i];
    }
    float bias = b_ih[j] + b_hh[j];

#pragma unroll
    for (int r = 0; r < 8; ++r) {
        int v = vbase + r;
        float x[32];
        const float4* xp = (const float4*)(emb + v * 32);
#pragma unroll
        for (int i = 0; i < 8; ++i) *((float4*)x + i) = xp[i];
        float a0 = bias, a1 = 0.f;
#pragma unroll
        for (int i = 0; i < 16; ++i) {
            a0 += x[2*i]   * w[2*i];
            a1 += x[2*i+1] * w[2*i+1];
        }
        proj[(size_t)v * 64 + j] = a0 + a1;
    }
}

// ---------------------------------------------------------------------------
// Kernel 1 (fused): blocks 0..31 = LSTM recurrence (wave 0 only, reads proj);
// blocks 32..563 = W_out/b_out fp32->bf16 convert.  (R2-verified form.)
// Convert runs on CUs idle during the serial LSTM.
// ---------------------------------------------------------------------------
__global__ __launch_bounds__(256) void k_mid(
    const int* __restrict__ idx,
    const float* __restrict__ proj,
    const float* __restrict__ W_hh,
    const float* __restrict__ h0,
    const float* __restrict__ c0,
    unsigned short* __restrict__ h_ws,
    const float* __restrict__ W_out,
    const float* __restrict__ b_out,
    unsigned short* __restrict__ Wo16,
    unsigned short* __restrict__ bo16)
{
    int bx = blockIdx.x;
    if (bx < 32) {
        if (threadIdx.x >= 64) return;
        int b = bx;
        int j = threadIdx.x;

        float w[16];
        {
            const float4* wp = (const float4*)(W_hh + j * 16);
#pragma unroll
            for (int i = 0; i < 4; ++i) *((float4*)w + i) = wp[i];
        }

        int l15 = j & 15;
        float h = h0[b * HIDDEN + l15];
        float c = c0[b * HIDDEN + l15];

        int i0 = idx[j * BATCH + b];
        int i1 = idx[(j + 64) * BATCH + b];

        float xg0 = proj[(size_t)__shfl(i0, 0) * 64 + j];
        float xg1 = proj[(size_t)__shfl(i0, 1) * 64 + j];

        for (int s = 0; s < SEQ; ++s) {
            float xg = xg0;
            xg0 = xg1;
            if (s + 2 < SEQ) {
                int sn = s + 2;
                int idn = __shfl((sn < 64) ? i0 : i1, sn & 63);
                xg1 = proj[(size_t)idn * 64 + j];
            }

            float a0 = xg, a1 = 0.f;
#pragma unroll
            for (int k = 0; k < 8; ++k) {
                a0 += w[2*k]   * __shfl(h, 2*k);
                a1 += w[2*k+1] * __shfl(h, 2*k+1);
            }
            float acc = a0 + a1;

            float e1 = fexp2(-acc * LOG2E);
            float sg = frcp(1.f + e1);
            float e2 = fexp2(-2.f * acc * LOG2E);
            float th = 2.f * frcp(1.f + e2) - 1.f;
            float act = ((j >> 4) == 2) ? th : sg;

            float i_ = __shfl(act, l15);
            float f_ = __shfl(act, l15 + 16);
            float g_ = __shfl(act, l15 + 32);
            float o_ = __shfl(act, l15 + 48);

            c = f_ * c + i_ * g_;
            float e3 = fexp2(-2.f * c * LOG2E);
            float hc = 2.f * frcp(1.f + e3) - 1.f;   // tanh(c)
            h = o_ * hc;

            if (j < 16)
                h_ws[(size_t)(s * BATCH + b) * HIDDEN + j] = f2bf(h);
        }
    } else {
        int t4 = ((bx - 32) * 256 + threadIdx.x) * 4;
        const int NW = VOCAB * HIDDEN;                 // 512000
        if (t4 < NW) {
            float4 v = *(const float4*)(W_out + t4);
            Wo16[t4 + 0] = f2bf(v.x); Wo16[t4 + 1] = f2bf(v.y);
            Wo16[t4 + 2] = f2bf(v.z); Wo16[t4 + 3] = f2bf(v.w);
        } else if (t4 < NW + VOCAB) {
            int j = t4 - NW;
            float4 v = *(const float4*)(b_out + j);
            bo16[j + 0] = f2bf(v.x); bo16[j + 1] = f2bf(v.y);
            bo16[j + 2] = f2bf(v.z); bo16[j + 3] = f2bf(v.w);
        }
    }
}

// ---------------------------------------------------------------------------
// Kernel 2 (merged LSE + write): 256 blocks x 1024 thr (16 waves), exactly
// one block per CU (single block-wave, zero ramp/drain tail). Block owns
// 16 (s,b) rows x FULL vocab -> both softmax passes run in-block with one
// __syncthreads; no cross-block dependency, no gsum, no atomics, no second
// launch. Wo16 (1 MB) stays hot in the XCD L2 between passes.
//   pass 1: per-wave 125 tiles, MFMA 16x16x32 bf16 (K-slot 16 = bias),
//           exp2 accumulate -> LDS reduce over 16 waves -> K = ln(sum).
//   pass 2: same tiles; -K folded into MFMA C-operand; wave-local LDS
//           transpose (XOR-swizzled) -> each store covers 4 rows x 256 B
//           contiguous (full L2 lines).
// Logits bounded (|h|<1, |W|,|b|<=0.25): no max-subtraction needed.
// ---------------------------------------------------------------------------
__global__ __launch_bounds__(1024, 4) void k_out(
    const unsigned short* __restrict__ Wo16,
    const unsigned short* __restrict__ bo16,
    const unsigned short* __restrict__ h_ws,
    float* __restrict__ out)
{
    __shared__ float sums[16][16];
    __shared__ float lds[16][1024];   // 4 KB per wave (16 rows x 64 vocab fp32)

    int r0   = blockIdx.x * 16;
    int tid  = threadIdx.x;
    int wave = tid >> 6;
    int lane = tid & 63;
    int n = lane & 15;        // B column (s,b row) / A row (vocab) local idx
    int q = lane >> 4;        // quad

    short8 bfrag = {0, 0, 0, 0, 0, 0, 0, 0};
    if (q < 2)
        bfrag = *(const short8*)(h_ws + (size_t)(r0 + n) * 16 + 8 * q);
    else if (q == 2)
        bfrag[0] = (short)0x3F80;   // 1.0 bf16 in K-slot 16 (bias row)

    const int t0 = wave * TPW_OUT;

    // ---- pass 1: per-row sum of exp(y) ----
    float s0 = 0.f, s1 = 0.f, s2 = 0.f, s3 = 0.f;

    for (int ss = 0; ss < 31; ++ss) {
        int tb = t0 + ss * 4;
        short8 A[4];
#pragma unroll
        for (int t = 0; t < 4; ++t) {
            short8 a = {0, 0, 0, 0, 0, 0, 0, 0};
            int v0 = (tb + t) * 16;
            if (q < 2)       a = *(const short8*)(Wo16 + (size_t)(v0 + n) * 16 + 8 * q);
            else if (q == 2) a[0] = (short)bo16[v0 + n];
            A[t] = a;
        }
#pragma unroll
        for (int t = 0; t < 4; ++t) {
            float4v dz = {0.f, 0.f, 0.f, 0.f};
            float4v d = __builtin_amdgcn_mfma_f32_16x16x32_bf16(A[t], bfrag, dz, 0, 0, 0);
            s0 += fexp2(d[0] * LOG2E);
            s1 += fexp2(d[1] * LOG2E);
            s2 += fexp2(d[2] * LOG2E);
            s3 += fexp2(d[3] * LOG2E);
        }
    }
    {   // tail tile (125th)
        int v0 = (t0 + 124) * 16;
        short8 a = {0, 0, 0, 0, 0, 0, 0, 0};
        if (q < 2)       a = *(const short8*)(Wo16 + (size_t)(v0 + n) * 16 + 8 * q);
        else if (q == 2) a[0] = (short)bo16[v0 + n];
        float4v dz = {0.f, 0.f, 0.f, 0.f};
        float4v d = __builtin_amdgcn_mfma_f32_16x16x32_bf16(a, bfrag, dz, 0, 0, 0);
        s0 += fexp2(d[0] * LOG2E);
        s1 += fexp2(d[1] * LOG2E);
        s2 += fexp2(d[2] * LOG2E);
        s3 += fexp2(d[3] * LOG2E);
    }

    float ssum = (s0 + s1) + (s2 + s3);
    ssum += __shfl_xor(ssum, 16);
    ssum += __shfl_xor(ssum, 32);
    if (q == 0) sums[wave][n] = ssum;
    __syncthreads();

    float tot = 0.f;
#pragma unroll
    for (int wv = 0; wv < 16; ++wv) tot += sums[wv][n];
    float K = flog2(tot) * LN2;            // ln(sum exp(y)) for row r0+n
    float4v cinit = {-K, -K, -K, -K};      // folded into MFMA C-operand

    // ---- pass 2: recompute logits, y - K, LDS-transposed coalesced store ----
    float* wl = lds[wave];
    for (int ss = 0; ss < 31; ++ss) {
        int tb = t0 + ss * 4;
        short8 A[4];
#pragma unroll
        for (int t = 0; t < 4; ++t) {
            short8 a = {0, 0, 0, 0, 0, 0, 0, 0};
            int v0 = (tb + t) * 16;
            if (q < 2)       a = *(const short8*)(Wo16 + (size_t)(v0 + n) * 16 + 8 * q);
            else if (q == 2) a[0] = (short)bo16[v0 + n];
            A[t] = a;
        }
        // MFMA(+C=-K) + swizzled LDS stage (value = row n, vocab unit u)
#pragma unroll
        for (int t = 0; t < 4; ++t) {
            float4v d = __builtin_amdgcn_mfma_f32_16x16x32_bf16(A[t], bfrag, cinit, 0, 0, 0);
            int u = t * 4 + q;                       // 16B-unit within 64-vocab tile
            *(float4v*)(wl + (size_t)(n * 16 + (u ^ n)) * 4) = d;
        }
        // transpose-read + contiguous store: instr k = rows 4k+q, unit n
        int V0 = tb * 16;
#pragma unroll
        for (int k = 0; k < 4; ++k) {
            int rr = 4 * k + q;                      // row within rowgroup
            float4v val = *(const float4v*)(wl + (size_t)(rr * 16 + (n ^ rr)) * 4);
            *(float4v*)(out + (size_t)(r0 + rr) * VOCAB + V0 + n * 4) = val;
        }
    }
    {   // tail tile (direct store)
        int v0 = (t0 + 124) * 16;
        short8 a = {0, 0, 0, 0, 0, 0, 0, 0};
        if (q < 2)       a = *(const short8*)(Wo16 + (size_t)(v0 + n) * 16 + 8 * q);
        else if (q == 2) a[0] = (short)bo16[v0 + n];
        float4v d = __builtin_amdgcn_mfma_f32_16x16x32_bf16(a, bfrag, cinit, 0, 0, 0);
        *(float4v*)(out + (size_t)(r0 + n) * VOCAB + v0 + 4 * q) = d;
    }
}

// ---------------------------------------------------------------------------
extern "C" void kernel_launch(void* const* d_in, const int* in_sizes, int n_in,
                              void* d_out, int out_size, void* d_ws, size_t ws_size,
                              hipStream_t stream)
{
    const int*   idx   = (const int*)d_in[0];
    const float* emb   = (const float*)d_in[1];
    const float* W_ih  = (const float*)d_in[2];
    const float* W_hh  = (const float*)d_in[3];
    const float* b_ih  = (const float*)d_in[4];
    const float* b_hh  = (const float*)d_in[5];
    const float* W_out = (const float*)d_in[6];
    const float* b_out = (const float*)d_in[7];
    const float* h0    = (const float*)d_in[8];
    const float* c0    = (const float*)d_in[9];

    // workspace layout:
    //   proj  [32000][64] fp32 : 8.192 MB
    //   Wo16  [32000][16] bf16 : 1.024 MB
    //   bo16  [32000]     bf16 : 64 KB
    //   h_ws  [4096][16]  bf16 : 128 KB
    char* p = (char*)d_ws;
    float*          proj = (float*)p;                      p += (size_t)VOCAB * 64 * 4;
    unsigned short* Wo16 = (unsigned short*)p;             p += (size_t)VOCAB * 16 * 2;
    unsigned short* bo16 = (unsigned short*)p;             p += (size_t)VOCAB * 2;
    unsigned short* h_ws = (unsigned short*)p;

    k_prep<<<1000, 256, 0, stream>>>(emb, W_ih, b_ih, b_hh, proj);
    k_mid<<<564, 256, 0, stream>>>(idx, proj, W_hh, h0, c0, h_ws,
                                   W_out, b_out, Wo16, bo16);
    k_out<<<SEQ * BATCH / 16, 1024, 0, stream>>>(Wo16, bo16, h_ws, (float*)d_out);
}

// Round 6
// 664.872 us; speedup vs baseline: 1.1134x; 1.1134x over previous
//
#include <hip/hip_runtime.h>
#include <hip/hip_bf16.h>

#define VOCAB  32000
#define EMBED  32
#define HIDDEN 16
#define SEQ    128
#define BATCH  32

typedef __attribute__((ext_vector_type(8))) short short8;
typedef __attribute__((ext_vector_type(4))) float float4v;

#define LOG2E 1.4426950408889634f
#define LN2   0.6931471805599453f

// vocab tiling for the logits kernels
#define NSLICE 10                  // vocab slices per row-group
#define TPB    200                 // 16-row vocab tiles per block (2000/NSLICE)
#define TPW    25                  // tiles per wave (TPB / 8 waves): 6x4 + 1 tail
#define NTILES 2000                // VOCAB / 16

__device__ __forceinline__ float fexp2(float x) { return __builtin_amdgcn_exp2f(x); }
__device__ __forceinline__ float frcp(float x)  { return __builtin_amdgcn_rcpf(x); }
__device__ __forceinline__ float flog2(float x) { return __builtin_amdgcn_logf(x); }

// RTNE float -> bf16 bits (finite inputs only)
__device__ __forceinline__ unsigned short f2bf(float x) {
    unsigned u = __float_as_uint(x);
    unsigned r = u + 0x7fffu + ((u >> 16) & 1u);
    return (unsigned short)(r >> 16);
}

// ---------------------------------------------------------------------------
// Kernel 0: proj[v][j] = emb[v]·W_ih[j] + b_ih[j] + b_hh[j]   (fp32)
// 1000 blocks x 256 thr.  (R2-verified form.)
// ---------------------------------------------------------------------------
__global__ __launch_bounds__(256) void k_prep(
    const float* __restrict__ emb,
    const float* __restrict__ W_ih,
    const float* __restrict__ b_ih,
    const float* __restrict__ b_hh,
    float* __restrict__ proj)
{
    int j  = threadIdx.x & 63;
    int vl = threadIdx.x >> 6;          // 0..3
    int vbase = blockIdx.x * 32 + vl * 8;

    float w[32];
    {
        const float4* wp = (const float4*)(W_ih + j * 32);
#pragma unroll
        for (int i = 0; i < 8; ++i) *((float4*)w + i) = wp[i];
    }
    float bias = b_ih[j] + b_hh[j];

#pragma unroll
    for (int r = 0; r < 8; ++r) {
        int v = vbase + r;
        float x[32];
        const float4* xp = (const float4*)(emb + v * 32);
#pragma unroll
        for (int i = 0; i < 8; ++i) *((float4*)x + i) = xp[i];
        float a0 = bias, a1 = 0.f;
#pragma unroll
        for (int i = 0; i < 16; ++i) {
            a0 += x[2*i]   * w[2*i];
            a1 += x[2*i+1] * w[2*i+1];
        }
        proj[(size_t)v * 64 + j] = a0 + a1;
    }
}

// ---------------------------------------------------------------------------
// Kernel 1 (fused): blocks 0..31 = LSTM recurrence (wave 0 only, reads proj);
// blocks 32..531 = build Apack (per-lane MFMA A-fragments, bf16, bias and
// zeros embedded); block 532 = zero gsum.
// Apack[t][lane][8 bf16]: q<2 -> W_out[t*16+n][8q..8q+7]; q==2 -> bias at
// K-slot 16; q==3 -> zeros. One uniform dwordx4 per tile in the hot kernels.
// ---------------------------------------------------------------------------
__global__ __launch_bounds__(256) void k_mid(
    const int* __restrict__ idx,
    const float* __restrict__ proj,
    const float* __restrict__ W_hh,
    const float* __restrict__ h0,
    const float* __restrict__ c0,
    unsigned short* __restrict__ h_ws,
    const float* __restrict__ W_out,
    const float* __restrict__ b_out,
    short8* __restrict__ Apack,
    float* __restrict__ gsum)
{
    int bx = blockIdx.x;
    if (bx < 32) {
        if (threadIdx.x >= 64) return;
        int b = bx;
        int j = threadIdx.x;

        float w[16];
        {
            const float4* wp = (const float4*)(W_hh + j * 16);
#pragma unroll
            for (int i = 0; i < 4; ++i) *((float4*)w + i) = wp[i];
        }

        int l15 = j & 15;
        float h = h0[b * HIDDEN + l15];
        float c = c0[b * HIDDEN + l15];

        int i0 = idx[j * BATCH + b];
        int i1 = idx[(j + 64) * BATCH + b];

        float xg0 = proj[(size_t)__shfl(i0, 0) * 64 + j];
        float xg1 = proj[(size_t)__shfl(i0, 1) * 64 + j];

        for (int s = 0; s < SEQ; ++s) {
            float xg = xg0;
            xg0 = xg1;
            if (s + 2 < SEQ) {
                int sn = s + 2;
                int idn = __shfl((sn < 64) ? i0 : i1, sn & 63);
                xg1 = proj[(size_t)idn * 64 + j];
            }

            float a0 = xg, a1 = 0.f;
#pragma unroll
            for (int k = 0; k < 8; ++k) {
                a0 += w[2*k]   * __shfl(h, 2*k);
                a1 += w[2*k+1] * __shfl(h, 2*k+1);
            }
            float acc = a0 + a1;

            float e1 = fexp2(-acc * LOG2E);
            float sg = frcp(1.f + e1);
            float e2 = fexp2(-2.f * acc * LOG2E);
            float th = 2.f * frcp(1.f + e2) - 1.f;
            float act = ((j >> 4) == 2) ? th : sg;

            float i_ = __shfl(act, l15);
            float f_ = __shfl(act, l15 + 16);
            float g_ = __shfl(act, l15 + 32);
            float o_ = __shfl(act, l15 + 48);

            c = f_ * c + i_ * g_;
            float e3 = fexp2(-2.f * c * LOG2E);
            float hc = 2.f * frcp(1.f + e3) - 1.f;   // tanh(c)
            h = o_ * hc;

            if (j < 16)
                h_ws[(size_t)(s * BATCH + b) * HIDDEN + j] = f2bf(h);
        }
    } else if (bx < 532) {
        // ---- build Apack: 500 blocks x 256 thr = 128000 = NTILES*64 cells ----
        int cell = (bx - 32) * 256 + threadIdx.x;
        int l = cell & 63;
        int n = l & 15;
        int q = l >> 4;
        int v = (cell >> 6) * 16 + n;              // vocab row
        short8 pk = {0, 0, 0, 0, 0, 0, 0, 0};
        if (q < 2) {
            const float4* wp = (const float4*)(W_out + (size_t)v * 16 + 8 * q);
            float4 w0 = wp[0], w1 = wp[1];
            pk[0] = (short)f2bf(w0.x); pk[1] = (short)f2bf(w0.y);
            pk[2] = (short)f2bf(w0.z); pk[3] = (short)f2bf(w0.w);
            pk[4] = (short)f2bf(w1.x); pk[5] = (short)f2bf(w1.y);
            pk[6] = (short)f2bf(w1.z); pk[7] = (short)f2bf(w1.w);
        } else if (q == 2) {
            pk[0] = (short)f2bf(b_out[v]);         // bias in K-slot 16
        }
        Apack[cell] = pk;                          // consecutive 16B: coalesced
    } else {
        for (int i = threadIdx.x; i < 1024; i += 256)
            ((float4*)gsum)[i] = make_float4(0.f, 0.f, 0.f, 0.f);
    }
}

// ---------------------------------------------------------------------------
// Kernel 2: partial log-sum-exp. grid 2560 (rg = bid/NSLICE), 512 thr.
// ONE uniform global_load_dwordx4 per tile (Apack), no divergence.
// 4-tile load groups + 1 tail tile.
// Logits bounded (|h|<1, |W|,|b|<=0.25): no max-subtraction needed.
// ---------------------------------------------------------------------------
__global__ __launch_bounds__(512, 4) void k_lse(
    const short8* __restrict__ Apack,
    const unsigned short* __restrict__ h_ws,
    float* __restrict__ gsum)
{
    __shared__ float sums[8][16];

    int bid  = blockIdx.x;
    int rg   = bid / NSLICE;
    int sl   = bid - rg * NSLICE;
    int r0   = rg * 16;
    int tid  = threadIdx.x;
    int wave = tid >> 6;
    int lane = tid & 63;
    int n = lane & 15;
    int q = lane >> 4;

    short8 bfrag = {0, 0, 0, 0, 0, 0, 0, 0};
    if (q < 2)
        bfrag = *(const short8*)(h_ws + (size_t)(r0 + n) * 16 + 8 * q);
    else if (q == 2)
        bfrag[0] = (short)0x3F80;   // 1.0 bf16 in K-slot 16 (bias row)

    int t0 = sl * TPB + wave * TPW;
    const short8* Ap = Apack + (size_t)t0 * 64 + lane;

    float s0 = 0.f, s1 = 0.f, s2 = 0.f, s3 = 0.f;

    for (int ss = 0; ss < 6; ++ss) {
        short8 A[4];
#pragma unroll
        for (int t = 0; t < 4; ++t) A[t] = Ap[(size_t)(ss * 4 + t) * 64];
#pragma unroll
        for (int t = 0; t < 4; ++t) {
            float4v dz = {0.f, 0.f, 0.f, 0.f};
            float4v d = __builtin_amdgcn_mfma_f32_16x16x32_bf16(A[t], bfrag, dz, 0, 0, 0);
            s0 += fexp2(d[0] * LOG2E);
            s1 += fexp2(d[1] * LOG2E);
            s2 += fexp2(d[2] * LOG2E);
            s3 += fexp2(d[3] * LOG2E);
        }
    }
    {   // tail tile (25th)
        short8 a = Ap[(size_t)24 * 64];
        float4v dz = {0.f, 0.f, 0.f, 0.f};
        float4v d = __builtin_amdgcn_mfma_f32_16x16x32_bf16(a, bfrag, dz, 0, 0, 0);
        s0 += fexp2(d[0] * LOG2E);
        s1 += fexp2(d[1] * LOG2E);
        s2 += fexp2(d[2] * LOG2E);
        s3 += fexp2(d[3] * LOG2E);
    }

    float ssum = (s0 + s1) + (s2 + s3);
    ssum += __shfl_xor(ssum, 16);
    ssum += __shfl_xor(ssum, 32);
    if (q == 0) sums[wave][n] = ssum;
    __syncthreads();

    if (tid < 16) {
        float tot = 0.f;
#pragma unroll
        for (int wv = 0; wv < 8; ++wv) tot += sums[wv][tid];
        atomicAdd(&gsum[r0 + tid], tot);   // device-scope, cross-XCD safe
    }
}

// ---------------------------------------------------------------------------
// Kernel 3: recompute logits (-K folded into MFMA C), store fp32.
// ONE uniform dwordx4 per tile (Apack). Wave-local LDS transpose
// (XOR-swizzled): each store covers 4 rows x 256 B contiguous.
// ---------------------------------------------------------------------------
__global__ __launch_bounds__(512, 4) void k_write(
    const short8* __restrict__ Apack,
    const unsigned short* __restrict__ h_ws,
    const float* __restrict__ gsum,
    float* __restrict__ out)
{
    __shared__ float lds[8][1024];   // 4 KB per wave (16 rows x 64 vocab fp32)

    int bid  = blockIdx.x;
    int rg   = bid / NSLICE;
    int sl   = bid - rg * NSLICE;
    int r0   = rg * 16;
    int tid  = threadIdx.x;
    int wave = tid >> 6;
    int lane = tid & 63;
    int n = lane & 15;
    int q = lane >> 4;
    float* wl = lds[wave];

    short8 bfrag = {0, 0, 0, 0, 0, 0, 0, 0};
    if (q < 2)
        bfrag = *(const short8*)(h_ws + (size_t)(r0 + n) * 16 + 8 * q);
    else if (q == 2)
        bfrag[0] = (short)0x3F80;

    float K = flog2(gsum[r0 + n]) * LN2;   // ln(sum exp(y)) for row r0+n
    float4v cinit = {-K, -K, -K, -K};      // folded into MFMA C-operand

    int t0 = sl * TPB + wave * TPW;
    const short8* Ap = Apack + (size_t)t0 * 64 + lane;

    for (int ss = 0; ss < 6; ++ss) {
        int tb = t0 + ss * 4;
        short8 A[4];
#pragma unroll
        for (int t = 0; t < 4; ++t) A[t] = Ap[(size_t)(ss * 4 + t) * 64];
        // MFMA(+C=-K) + swizzled LDS stage (value = row n, vocab unit u)
#pragma unroll
        for (int t = 0; t < 4; ++t) {
            float4v d = __builtin_amdgcn_mfma_f32_16x16x32_bf16(A[t], bfrag, cinit, 0, 0, 0);
            int u = t * 4 + q;                       // 16B-unit within 64-vocab tile
            *(float4v*)(wl + (size_t)(n * 16 + (u ^ n)) * 4) = d;
        }
        // transpose-read + contiguous store: instr k = rows 4k+q, unit n
        int V0 = tb * 16;
#pragma unroll
        for (int k = 0; k < 4; ++k) {
            int rr = 4 * k + q;                      // row within rowgroup
            float4v val = *(const float4v*)(wl + (size_t)(rr * 16 + (n ^ rr)) * 4);
            *(float4v*)(out + (size_t)(r0 + rr) * VOCAB + V0 + n * 4) = val;
        }
    }
    {   // tail tile (direct store)
        int v0 = (t0 + 24) * 16;
        short8 a = Ap[(size_t)24 * 64];
        float4v d = __builtin_amdgcn_mfma_f32_16x16x32_bf16(a, bfrag, cinit, 0, 0, 0);
        *(float4v*)(out + (size_t)(r0 + n) * VOCAB + v0 + 4 * q) = d;
    }
}

// ---------------------------------------------------------------------------
extern "C" void kernel_launch(void* const* d_in, const int* in_sizes, int n_in,
                              void* d_out, int out_size, void* d_ws, size_t ws_size,
                              hipStream_t stream)
{
    const int*   idx   = (const int*)d_in[0];
    const float* emb   = (const float*)d_in[1];
    const float* W_ih  = (const float*)d_in[2];
    const float* W_hh  = (const float*)d_in[3];
    const float* b_ih  = (const float*)d_in[4];
    const float* b_hh  = (const float*)d_in[5];
    const float* W_out = (const float*)d_in[6];
    const float* b_out = (const float*)d_in[7];
    const float* h0    = (const float*)d_in[8];
    const float* c0    = (const float*)d_in[9];

    // workspace layout:
    //   proj  [32000][64] fp32       : 8.192 MB
    //   Apack [2000][64] x 16B       : 2.048 MB
    //   h_ws  [4096][16]  bf16       : 128 KB
    //   gsum  [4096]      fp32       : 16 KB
    char* p = (char*)d_ws;
    float*          proj  = (float*)p;                     p += (size_t)VOCAB * 64 * 4;
    short8*         Apack = (short8*)p;                    p += (size_t)NTILES * 64 * 16;
    unsigned short* h_ws  = (unsigned short*)p;            p += (size_t)SEQ * BATCH * HIDDEN * 2;
    float*          gsum  = (float*)p;

    k_prep<<<1000, 256, 0, stream>>>(emb, W_ih, b_ih, b_hh, proj);
    k_mid<<<533, 256, 0, stream>>>(idx, proj, W_hh, h0, c0, h_ws,
                                   W_out, b_out, Apack, gsum);
    k_lse<<<SEQ * BATCH / 16 * NSLICE, 512, 0, stream>>>(Apack, h_ws, gsum);
    k_write<<<SEQ * BATCH / 16 * NSLICE, 512, 0, stream>>>(Apack, h_ws, gsum,
                                                           (float*)d_out);
}